// Round 7
// baseline (67.942 us; speedup 1.0000x reference)
//
#include <hip/hip_runtime.h>
#include <hip/hip_bf16.h>

// Problem constants (fixed by setup_inputs)
#define BB   4
#define CF   256
#define CC   64
#define CP   80
#define HH   128   // hi-res
#define WW   128
#define KK   25
#define NPIX 16384 // 128*128

typedef __attribute__((ext_vector_type(8))) short short8v;
typedef __attribute__((ext_vector_type(4))) short short4v;
typedef __attribute__((ext_vector_type(4))) float f32x4;
typedef __attribute__((ext_vector_type(2))) float f32x2;

static __device__ __forceinline__ short f2bf(float f) {
  __hip_bfloat16 h = __float2bfloat16(f);
  return *reinterpret_cast<short*>(&h);
}

// =================== K1: compress (1x1 conv) via bf16 MFMA ==============
// guide[b][y][x][c] bf16 = sum_c' feat[b][c'][y][x] * wc[c][c'] + bc[c]
// grid 1024 = 4 b x 128 y x 2 x-halves (64 px). block 256 (4 waves).
// (unchanged from round 6 — measured at its HBM floor ~12-13 us)
__global__ __launch_bounds__(256) void k_compress(
    const float* __restrict__ feat, const float* __restrict__ wc,
    const float* __restrict__ bc, const float* __restrict__ we,
    short* __restrict__ guide, short* __restrict__ web) {
  __shared__ short Al[32 * 520];  // [(cblk*4+lh)][o(64)*8], pad 512->520
  __shared__ short Bl[64 * 72];   // [px][c 0..63], stride 72
  const int tid = threadIdx.x;
  const int bx = blockIdx.x;
  const int b = bx >> 8;
  const int y = (bx >> 1) & 127;
  const int x0 = (bx & 1) << 6;

  // distributed web prestage: web[tap][kk pad32][c], zero for kk>=25
  {
    int j = bx * 256 + tid;
    if (j < 9 * 32 * 64) {
      int tap = j >> 11, kk = (j >> 6) & 31, c = j & 63;
      float v = (kk < KK) ? we[(kk * 64 + c) * 9 + tap] : 0.f;
      web[j] = f2bf(v);
    }
  }

  // convert wc (64x256 f32) -> Al in fragment order
#pragma unroll
  for (int t = 0; t < 8; ++t) {
    int idx = tid + t * 256;  // 0..2047
    int o = idx >> 5, c8 = idx & 31;
    const f32x4* src = (const f32x4*)(wc + o * CF + c8 * 8);
    f32x4 v0 = src[0], v1 = src[1];
    short8v h;
    h[0] = f2bf(v0.x); h[1] = f2bf(v0.y); h[2] = f2bf(v0.z); h[3] = f2bf(v0.w);
    h[4] = f2bf(v1.x); h[5] = f2bf(v1.y); h[6] = f2bf(v1.z); h[7] = f2bf(v1.w);
    int cblk = c8 >> 2, lh4 = c8 & 3;
    *(short8v*)(Al + (cblk * 4 + lh4) * 520 + o * 8) = h;
  }

  const int wave = tid >> 6, l = tid & 63;
  const int l15 = l & 15, lh = l >> 4;
  const int px_s = tid & 63;          // staging pixel
  const int c_s = (tid >> 6) << 4;    // staging channel offset (16/wave)
  const float* fb = feat + (size_t)b * CF * NPIX + y * WW + x0;

  f32x4 acc[4];
#pragma unroll
  for (int m = 0; m < 4; ++m) acc[m] = (f32x4){0.f, 0.f, 0.f, 0.f};

  for (int c0 = 0; c0 < CF; c0 += 64) {
    if (c0) __syncthreads();
    float v[16];
#pragma unroll
    for (int i = 0; i < 16; ++i)
      v[i] = fb[(size_t)(c0 + c_s + i) * NPIX + px_s];
    short8v h0, h1;
#pragma unroll
    for (int e = 0; e < 8; ++e) { h0[e] = f2bf(v[e]); h1[e] = f2bf(v[8 + e]); }
    *(short8v*)(Bl + px_s * 72 + c_s) = h0;
    *(short8v*)(Bl + px_s * 72 + c_s + 8) = h1;
    __syncthreads();  // Bl (and, first pass, Al) visible
#pragma unroll
    for (int ks = 0; ks < 64; ks += 32) {
      const int cblk = (c0 + ks) >> 5;
      short8v bfr = *(const short8v*)(Bl + (wave * 16 + l15) * 72 + ks + lh * 8);
#pragma unroll
      for (int m = 0; m < 4; ++m) {
        short8v a = *(const short8v*)(Al + (cblk * 4 + lh) * 520 +
                                      (m * 16 + l15) * 8);
        acc[m] = __builtin_amdgcn_mfma_f32_16x16x32_bf16(a, bfr, acc[m], 0, 0, 0);
      }
    }
  }

  // epilogue: +bias, cvt bf16, store [b][y][x][c]
  const int px = wave * 16 + l15;
  short* gb = guide + ((size_t)((b * HH + y) * WW + x0 + px)) * CC;
#pragma unroll
  for (int m = 0; m < 4; ++m) {
    short4v o;
#pragma unroll
    for (int r = 0; r < 4; ++r) {
      int c = m * 16 + lh * 4 + r;
      o[r] = f2bf(acc[m][r] + bc[c]);
    }
    *(short4v*)(gb + m * 16 + lh * 4) = o;
  }
}

// ========= K2: conv3x3 + bias + softmax via MFMA — NO LDS version =======
// B-fragments read straight from L2-resident guide (clamped + predicated),
// A-fragments from L1-resident web. No staging, no __syncthreads.
// grid 1024 = 4 b x 16x16 tiles of 8x8 px. block 256 (4 waves).
__global__ __launch_bounds__(256) void k_conv(
    const short* __restrict__ guide, const short* __restrict__ web,
    const float* __restrict__ be, float* __restrict__ maskf) {
  const int tid = threadIdx.x;
  const int bx = blockIdx.x;
  const int b = bx >> 8;
  const int t = bx & 255;
  const int y0 = (t >> 4) << 3, x0 = (t & 15) << 3;
  const int wave = tid >> 6, l = tid & 63;
  const int l15 = l & 15, lh = l >> 4;

  const int r_ = wave * 2 + (l15 >> 3);  // tile row 0..7
  const int cx = l15 & 7;                // tile col 0..7
  const int Y = y0 + r_, X = x0 + cx;

  f32x4 acc0 = {0.f, 0.f, 0.f, 0.f}, acc1 = {0.f, 0.f, 0.f, 0.f};
#pragma unroll 3
  for (int tap = 0; tap < 9; ++tap) {
    const int dy = tap / 3, dx = tap - dy * 3;
    int gy = Y + dy - 1, gx = X + dx - 1;
    bool v = ((unsigned)gy < (unsigned)HH) && ((unsigned)gx < (unsigned)WW);
    int cy = v ? gy : 0, cz = v ? gx : 0;
    const short* gb2 = guide + ((size_t)((b * HH + cy) * WW + cz)) * CC + lh * 8;
    short8v bf0 = *(const short8v*)(gb2);
    short8v bf1 = *(const short8v*)(gb2 + 32);
    if (!v) {
      bf0 = (short8v){0, 0, 0, 0, 0, 0, 0, 0};
      bf1 = (short8v){0, 0, 0, 0, 0, 0, 0, 0};
    }
#pragma unroll
    for (int ks = 0; ks < 64; ks += 32) {
      short8v a0 = *(const short8v*)(web + (tap * 32 + l15) * 64 + ks + lh * 8);
      short8v a1 =
          *(const short8v*)(web + (tap * 32 + 16 + l15) * 64 + ks + lh * 8);
      short8v bf = ks ? bf1 : bf0;
      acc0 = __builtin_amdgcn_mfma_f32_16x16x32_bf16(a0, bf, acc0, 0, 0, 0);
      acc1 = __builtin_amdgcn_mfma_f32_16x16x32_bf16(a1, bf, acc1, 0, 0, 0);
    }
  }

  // ---- bias + softmax over kk (25 vals in 4 lanes: xor 16,32) ----
  float sv[8];
#pragma unroll
  for (int r = 0; r < 4; ++r) {
    int kk0 = lh * 4 + r;            // 0..15, always < 25
    sv[r] = acc0[r] + be[kk0];
    int kk1 = 16 + lh * 4 + r;       // 16..31
    sv[4 + r] = (kk1 < KK) ? (acc1[r] + be[kk1]) : -1e30f;
  }
  float mx = sv[0];
#pragma unroll
  for (int i = 1; i < 8; ++i) mx = fmaxf(mx, sv[i]);
  mx = fmaxf(mx, __shfl_xor(mx, 16));
  mx = fmaxf(mx, __shfl_xor(mx, 32));
  float s = 0.f;
#pragma unroll
  for (int i = 0; i < 8; ++i) {
    sv[i] = __expf(sv[i] - mx);
    s += sv[i];
  }
  s += __shfl_xor(s, 16);
  s += __shfl_xor(s, 32);
  float inv = 1.f / s;

  // store: maskf[b][Y][X][28] (kk>=25 pads are exp(-inf)=0)
  float* row = maskf + ((size_t)((b * HH + Y) * WW + X)) * 28;
  f32x4 o0 = {sv[0] * inv, sv[1] * inv, sv[2] * inv, sv[3] * inv};
  *(f32x4*)(row + lh * 4) = o0;
  if (lh < 3) {  // kk1 base 16,20,24
    f32x4 o1 = {sv[4] * inv, sv[5] * inv, sv[6] * inv, sv[7] * inv};
    *(f32x4*)(row + 16 + lh * 4) = o1;
  }
}

// ============= K3: CARAFE upsample — NO LDS version =====================
// Thread = (Y row, lo-x pair xp, 5-ch group). X = 2*xp, X+1 share the same
// 5x5 lo-res patch (up=2). Patch loads straight from L2-resident pred,
// coalesced along xp. Masks global->regs (m[2][25] = 50 VGPR). No syncs.
// grid 2048 = 4 b x 128 Y x 4 group-quads. block 256 = 4 groups x 64 xp.
__global__ __launch_bounds__(256) void k_carafe4(
    const float* __restrict__ pred, const float* __restrict__ maskf,
    float* __restrict__ out) {
  const int tid = threadIdx.x;
  const int bx = blockIdx.x;
  const int b = bx >> 9;
  const int t = bx & 511;
  const int Y = t >> 2;
  const int g = (t & 3) * 4 + (tid >> 6);  // ch-group 0..15 (5 ch each)
  const int xp = tid & 63;                 // lo-res x == pair id
  const int X = xp << 1;

  // ---- masks for the pair -> registers ----
  float m[2][KK];
#pragma unroll
  for (int dxp = 0; dxp < 2; ++dxp) {
    const f32x4* mp =
        (const f32x4*)(maskf + ((size_t)((b * HH + Y) * WW + X + dxp)) * 28);
#pragma unroll
    for (int v4 = 0; v4 < 7; ++v4) {
      f32x4 mv = mp[v4];
#pragma unroll
      for (int e = 0; e < 4; ++e) {
        int kk = v4 * 4 + e;
        if (kk < KK) m[dxp][kk] = mv[e];
      }
    }
  }

  // ---- reflect-padded patch offsets ----
  const int iy = Y >> 1;
  int ryo[5], rxo[5];
#pragma unroll
  for (int i = 0; i < 5; ++i) {
    int ry = iy - 2 + i;
    ry = ry < 0 ? -ry : (ry > 63 ? 126 - ry : ry);
    ryo[i] = ry << 6;
    int rx = xp - 2 + i;
    rx = rx < 0 ? -rx : (rx > 63 ? 126 - rx : rx);
    rxo[i] = rx;
  }

  // ---- 5 channels x 2 px ----
  for (int cc = 0; cc < 5; ++cc) {
    const int ch = g * 5 + cc;
    const float* pb = pred + ((size_t)(b * CP + ch) << 12);
    float a0 = 0.f, a1 = 0.f;
#pragma unroll
    for (int i = 0; i < 5; ++i)
#pragma unroll
      for (int j = 0; j < 5; ++j) {
        float p = pb[ryo[i] + rxo[j]];
        a0 += p * m[0][i * 5 + j];
        a1 += p * m[1][i * 5 + j];
      }
    f32x2 v2 = {a0, a1};
    *(f32x2*)(out + ((size_t)(b * CP + ch) << 14) + (Y << 7) + X) = v2;
  }
}

extern "C" void kernel_launch(void* const* d_in, const int* in_sizes, int n_in,
                              void* d_out, int out_size, void* d_ws,
                              size_t ws_size, hipStream_t stream) {
  (void)in_sizes; (void)n_in; (void)out_size; (void)ws_size;
  const float* pred = (const float*)d_in[0];  // (4,80,64,64)
  const float* feat = (const float*)d_in[1];  // (4,256,128,128)
  const float* wc   = (const float*)d_in[2];  // (64,256)
  const float* bc   = (const float*)d_in[3];  // (64)
  const float* we   = (const float*)d_in[4];  // (25,64,3,3)
  const float* be   = (const float*)d_in[5];  // (25)
  float* out = (float*)d_out;                 // (4,80,128,128)

  char* ws = (char*)d_ws;
  short* guide = (short*)ws;                    // 8,388,608 B bf16 [b][y][x][c]
  short* web   = (short*)(ws + 8388608);        // 36,864 B bf16 [tap][kk32][c]
  float* maskf = (float*)(ws + 8388608 + 36864);// 7,340,032 B f32 [b][Y][X][28]

  hipLaunchKernelGGL(k_compress, dim3(1024), dim3(256), 0, stream,
                     feat, wc, bc, we, guide, web);
  hipLaunchKernelGGL(k_conv, dim3(1024), dim3(256), 0, stream,
                     guide, web, be, maskf);
  hipLaunchKernelGGL(k_carafe4, dim3(2048), dim3(256), 0, stream,
                     pred, maskf, out);
}

// Round 8
// 60.852 us; speedup vs baseline: 1.1165x; 1.1165x over previous
//
#include <hip/hip_runtime.h>
#include <hip/hip_bf16.h>

// Problem constants (fixed by setup_inputs)
#define BB   4
#define CF   256
#define CC   64
#define CP   80
#define HH   128   // hi-res
#define WW   128
#define KK   25
#define NPIX 16384 // 128*128

typedef __attribute__((ext_vector_type(8))) short short8v;
typedef __attribute__((ext_vector_type(4))) short short4v;
typedef __attribute__((ext_vector_type(4))) float f32x4;
typedef __attribute__((ext_vector_type(2))) float f32x2;

static __device__ __forceinline__ short f2bf(float f) {
  __hip_bfloat16 h = __float2bfloat16(f);
  return *reinterpret_cast<short*>(&h);
}

// =================== K1: compress (1x1 conv) via bf16 MFMA ==============
// guide[b][y][x][c] bf16 = sum_c' feat[b][c'][y][x] * wc[c][c'] + bc[c]
// grid 1024 = 4 b x 128 y x 2 x-halves (64 px). block 256 (4 waves).
// (unchanged — HBM-bound at ~its floor)
__global__ __launch_bounds__(256) void k_compress(
    const float* __restrict__ feat, const float* __restrict__ wc,
    const float* __restrict__ bc, const float* __restrict__ we,
    short* __restrict__ guide, short* __restrict__ web) {
  __shared__ short Al[32 * 520];  // [(cblk*4+lh)][o(64)*8], pad 512->520
  __shared__ short Bl[64 * 72];   // [px][c 0..63], stride 72
  const int tid = threadIdx.x;
  const int bx = blockIdx.x;
  const int b = bx >> 8;
  const int y = (bx >> 1) & 127;
  const int x0 = (bx & 1) << 6;

  // distributed web prestage: web[tap][kk pad32][c], zero for kk>=25
  {
    int j = bx * 256 + tid;
    if (j < 9 * 32 * 64) {
      int tap = j >> 11, kk = (j >> 6) & 31, c = j & 63;
      float v = (kk < KK) ? we[(kk * 64 + c) * 9 + tap] : 0.f;
      web[j] = f2bf(v);
    }
  }

  // convert wc (64x256 f32) -> Al in fragment order
#pragma unroll
  for (int t = 0; t < 8; ++t) {
    int idx = tid + t * 256;  // 0..2047
    int o = idx >> 5, c8 = idx & 31;
    const f32x4* src = (const f32x4*)(wc + o * CF + c8 * 8);
    f32x4 v0 = src[0], v1 = src[1];
    short8v h;
    h[0] = f2bf(v0.x); h[1] = f2bf(v0.y); h[2] = f2bf(v0.z); h[3] = f2bf(v0.w);
    h[4] = f2bf(v1.x); h[5] = f2bf(v1.y); h[6] = f2bf(v1.z); h[7] = f2bf(v1.w);
    int cblk = c8 >> 2, lh4 = c8 & 3;
    *(short8v*)(Al + (cblk * 4 + lh4) * 520 + o * 8) = h;
  }

  const int wave = tid >> 6, l = tid & 63;
  const int l15 = l & 15, lh = l >> 4;
  const int px_s = tid & 63;          // staging pixel
  const int c_s = (tid >> 6) << 4;    // staging channel offset (16/wave)
  const float* fb = feat + (size_t)b * CF * NPIX + y * WW + x0;

  f32x4 acc[4];
#pragma unroll
  for (int m = 0; m < 4; ++m) acc[m] = (f32x4){0.f, 0.f, 0.f, 0.f};

  for (int c0 = 0; c0 < CF; c0 += 64) {
    if (c0) __syncthreads();
    float v[16];
#pragma unroll
    for (int i = 0; i < 16; ++i)
      v[i] = fb[(size_t)(c0 + c_s + i) * NPIX + px_s];
    short8v h0, h1;
#pragma unroll
    for (int e = 0; e < 8; ++e) { h0[e] = f2bf(v[e]); h1[e] = f2bf(v[8 + e]); }
    *(short8v*)(Bl + px_s * 72 + c_s) = h0;
    *(short8v*)(Bl + px_s * 72 + c_s + 8) = h1;
    __syncthreads();  // Bl (and, first pass, Al) visible
#pragma unroll
    for (int ks = 0; ks < 64; ks += 32) {
      const int cblk = (c0 + ks) >> 5;
      short8v bfr = *(const short8v*)(Bl + (wave * 16 + l15) * 72 + ks + lh * 8);
#pragma unroll
      for (int m = 0; m < 4; ++m) {
        short8v a = *(const short8v*)(Al + (cblk * 4 + lh) * 520 +
                                      (m * 16 + l15) * 8);
        acc[m] = __builtin_amdgcn_mfma_f32_16x16x32_bf16(a, bfr, acc[m], 0, 0, 0);
      }
    }
  }

  // epilogue: +bias, cvt bf16, store [b][y][x][c]
  const int px = wave * 16 + l15;
  short* gb = guide + ((size_t)((b * HH + y) * WW + x0 + px)) * CC;
#pragma unroll
  for (int m = 0; m < 4; ++m) {
    short4v o;
#pragma unroll
    for (int r = 0; r < 4; ++r) {
      int c = m * 16 + lh * 4 + r;
      o[r] = f2bf(acc[m][r] + bc[c]);
    }
    *(short4v*)(gb + m * 16 + lh * 4) = o;
  }
}

// ===== K2: conv3x3 + bias + softmax via MFMA — 4 sub-blocks per block ===
// Same per-tile body as round 6, but 256 blocks x 1024 threads (4 tiles
// per block) to cut total block count 4x. LDS 57.6 KB.
__global__ __launch_bounds__(1024) void k_conv(
    const short* __restrict__ guide, const short* __restrict__ web,
    const float* __restrict__ be, float* __restrict__ maskf) {
  __shared__ short Gl[4][7200];  // per sub-block [y'(10)][x'(10)][c], stride 72
  const int tid = threadIdx.x;
  const int sub = tid >> 8, stid = tid & 255;
  const int unit = blockIdx.x * 4 + sub;  // 0..1023
  const int b = unit >> 8;
  const int t = unit & 255;
  const int y0 = (t >> 4) << 3, x0 = (t & 15) << 3;
  const int wave = stid >> 6, l = stid & 63;
  const int l15 = l & 15, lh = l >> 4;

  // ---- stage guide halo tile (zero-pad) ----
  for (int idx = stid; idx < 10 * 10 * 8; idx += 256) {
    int yp = idx / 80;
    int rem = idx - yp * 80;
    int xp = rem >> 3, cq = (rem & 7) << 3;
    int gy = y0 - 1 + yp, gx = x0 - 1 + xp;
    short8v v = {0, 0, 0, 0, 0, 0, 0, 0};
    if (gy >= 0 && gy < HH && gx >= 0 && gx < WW)
      v = *(const short8v*)(guide + ((size_t)((b * HH + gy) * WW + gx)) * CC + cq);
    *(short8v*)(&Gl[sub][(yp * 10 + xp) * 72 + cq]) = v;
  }
  __syncthreads();

  // ---- conv MFMA: px = wave*16 + l15 -> (row, col) in 8x8 tile ----
  const int r_ = wave * 2 + (l15 >> 3);  // tile row 0..7
  const int cx = l15 & 7;                // tile col 0..7
  f32x4 acc0 = {0.f, 0.f, 0.f, 0.f}, acc1 = {0.f, 0.f, 0.f, 0.f};
#pragma unroll
  for (int tap = 0; tap < 9; ++tap) {
    const int dy = tap / 3, dx = tap - dy * 3;
#pragma unroll
    for (int ks = 0; ks < 64; ks += 32) {
      short8v a0 = *(const short8v*)(web + (tap * 32 + l15) * 64 + ks + lh * 8);
      short8v a1 =
          *(const short8v*)(web + (tap * 32 + 16 + l15) * 64 + ks + lh * 8);
      short8v bf = *(const short8v*)(&Gl[sub][((r_ + dy) * 10 + cx + dx) * 72 +
                                              ks + lh * 8]);
      acc0 = __builtin_amdgcn_mfma_f32_16x16x32_bf16(a0, bf, acc0, 0, 0, 0);
      acc1 = __builtin_amdgcn_mfma_f32_16x16x32_bf16(a1, bf, acc1, 0, 0, 0);
    }
  }

  // ---- bias + softmax over kk (25 vals in 4 lanes: xor 16,32) ----
  float sv[8];
#pragma unroll
  for (int r = 0; r < 4; ++r) {
    int kk0 = lh * 4 + r;            // 0..15, always < 25
    sv[r] = acc0[r] + be[kk0];
    int kk1 = 16 + lh * 4 + r;       // 16..31
    sv[4 + r] = (kk1 < KK) ? (acc1[r] + be[kk1]) : -1e30f;
  }
  float mx = sv[0];
#pragma unroll
  for (int i = 1; i < 8; ++i) mx = fmaxf(mx, sv[i]);
  mx = fmaxf(mx, __shfl_xor(mx, 16));
  mx = fmaxf(mx, __shfl_xor(mx, 32));
  float s = 0.f;
#pragma unroll
  for (int i = 0; i < 8; ++i) {
    sv[i] = __expf(sv[i] - mx);
    s += sv[i];
  }
  s += __shfl_xor(s, 16);
  s += __shfl_xor(s, 32);
  float inv = 1.f / s;

  // store: maskf[b][Y][X][28] (kk>=25 pads are 0)
  const int Y = y0 + r_, X = x0 + cx;
  float* row = maskf + ((size_t)((b * HH + Y) * WW + X)) * 28;
  f32x4 o0 = {sv[0] * inv, sv[1] * inv, sv[2] * inv, sv[3] * inv};
  *(f32x4*)(row + lh * 4) = o0;
  if (lh < 3) {  // kk1 base 16,20,24
    f32x4 o1 = {sv[4] * inv, sv[5] * inv, sv[6] * inv, sv[7] * inv};
    *(f32x4*)(row + 16 + lh * 4) = o1;
  }
}

// ===== K3: CARAFE upsample — 4 sub-blocks per block, 2 passes ===========
// Same per-unit body as round 6 k_carafe3 (unit = tile x ch-half), but
// 256 blocks x 1024 threads x 2 passes. LDS 51.2 KB.
__global__ __launch_bounds__(1024) void k_carafe(
    const float* __restrict__ pred, const float* __restrict__ maskf,
    float* __restrict__ out) {
  __shared__ float Pl[4][3200];  // per sub-block [cell 64][50]
  const int tid = threadIdx.x;
  const int sub = tid >> 8, stid = tid & 255;

  for (int pass = 0; pass < 2; ++pass) {
    if (pass) __syncthreads();  // protect Pl reuse (uniform control flow)
    const int unit = blockIdx.x * 4 + sub + pass * 1024;  // 0..2047
    const int half = unit & 1;
    const int t = (unit >> 1) & 255;
    const int b = unit >> 9;
    const int y0 = (t >> 4) << 3, x0 = (t & 15) << 3;

    // ---- stage Pl: 40 ch x 8x8 lo cells, reflect-padded ----
    const int ylo = (y0 >> 1) - 2, xlo = (x0 >> 1) - 2;
#pragma unroll
    for (int it = 0; it < 10; ++it) {
      int idx = it * 256 + stid;         // 0..2559
      int c = idx >> 6;                  // 0..39
      int cell = idx & 63;
      int r = cell >> 3, cl = cell & 7;
      int ry = ylo + r;
      ry = ry < 0 ? -ry : (ry > 63 ? 126 - ry : ry);
      int rx = xlo + cl;
      rx = rx < 0 ? -rx : (rx > 63 ? 126 - rx : rx);
      int gg = c / 5, cc = c - gg * 5;
      Pl[sub][cell * 50 + gg * 6 + cc] =
          pred[(((size_t)(b * CP + half * 40 + c)) << 12) + (ry << 6) + rx];
    }

    // ---- pair masks -> registers (global, L2/L3-hot) ----
    const int g = stid >> 5;             // 0..7 -> 5-ch group
    const int pr = stid & 31;            // pry(0..7) x prx(0..3)
    const int pry = pr >> 2, prx = pr & 3;
    const int Y = y0 + pry, X = x0 + prx * 2;
    float m[2][KK];
#pragma unroll
    for (int dxp = 0; dxp < 2; ++dxp) {
      const f32x4* mp =
          (const f32x4*)(maskf + ((size_t)((b * HH + Y) * WW + X + dxp)) * 28);
#pragma unroll
      for (int v4 = 0; v4 < 7; ++v4) {
        f32x4 mv = mp[v4];
#pragma unroll
        for (int e = 0; e < 4; ++e) {
          int kk = v4 * 4 + e;
          if (kk < KK) m[dxp][kk] = mv[e];
        }
      }
    }
    __syncthreads();  // Pl ready

    // ---- carafe: 5 ch x 2 px per thread ----
    float acc[5][2];
#pragma unroll
    for (int cc = 0; cc < 5; ++cc) { acc[cc][0] = 0.f; acc[cc][1] = 0.f; }

    const float* Pbase = &Pl[sub][((pry >> 1) * 8 + prx) * 50 + g * 6];
#pragma unroll
    for (int i = 0; i < 5; ++i)
#pragma unroll
      for (int j = 0; j < 5; ++j) {
        const float* P = Pbase + (i * 8 + j) * 50;
        f32x2 p01 = *(const f32x2*)(P);
        f32x2 p23 = *(const f32x2*)(P + 2);
        float p4 = P[4];
        float m0 = m[0][i * 5 + j], m1 = m[1][i * 5 + j];
        acc[0][0] += p01.x * m0; acc[0][1] += p01.x * m1;
        acc[1][0] += p01.y * m0; acc[1][1] += p01.y * m1;
        acc[2][0] += p23.x * m0; acc[2][1] += p23.x * m1;
        acc[3][0] += p23.y * m0; acc[3][1] += p23.y * m1;
        acc[4][0] += p4    * m0; acc[4][1] += p4    * m1;
      }

#pragma unroll
    for (int cc = 0; cc < 5; ++cc) {
      float* ob = out + (((size_t)(b * CP + half * 40 + g * 5 + cc)) << 14) +
                  Y * WW + X;
      f32x2 v2 = {acc[cc][0], acc[cc][1]};
      *(f32x2*)ob = v2;
    }
  }
}

extern "C" void kernel_launch(void* const* d_in, const int* in_sizes, int n_in,
                              void* d_out, int out_size, void* d_ws,
                              size_t ws_size, hipStream_t stream) {
  (void)in_sizes; (void)n_in; (void)out_size; (void)ws_size;
  const float* pred = (const float*)d_in[0];  // (4,80,64,64)
  const float* feat = (const float*)d_in[1];  // (4,256,128,128)
  const float* wc   = (const float*)d_in[2];  // (64,256)
  const float* bc   = (const float*)d_in[3];  // (64)
  const float* we   = (const float*)d_in[4];  // (25,64,3,3)
  const float* be   = (const float*)d_in[5];  // (25)
  float* out = (float*)d_out;                 // (4,80,128,128)

  char* ws = (char*)d_ws;
  short* guide = (short*)ws;                    // 8,388,608 B bf16 [b][y][x][c]
  short* web   = (short*)(ws + 8388608);        // 36,864 B bf16 [tap][kk32][c]
  float* maskf = (float*)(ws + 8388608 + 36864);// 7,340,032 B f32 [b][Y][X][28]

  hipLaunchKernelGGL(k_compress, dim3(1024), dim3(256), 0, stream,
                     feat, wc, bc, we, guide, web);
  hipLaunchKernelGGL(k_conv, dim3(256), dim3(1024), 0, stream,
                     guide, web, be, maskf);
  hipLaunchKernelGGL(k_carafe, dim3(256), dim3(1024), 0, stream,
                     pred, maskf, out);
}

// Round 9
// 56.084 us; speedup vs baseline: 1.2114x; 1.0850x over previous
//
#include <hip/hip_runtime.h>
#include <hip/hip_bf16.h>

// Problem constants (fixed by setup_inputs)
#define BB   4
#define CF   256
#define CC   64
#define CP   80
#define HH   128   // hi-res
#define WW   128
#define KK   25
#define NPIX 16384 // 128*128

typedef __attribute__((ext_vector_type(8))) short short8v;
typedef __attribute__((ext_vector_type(4))) short short4v;
typedef __attribute__((ext_vector_type(4))) float f32x4;
typedef __attribute__((ext_vector_type(2))) float f32x2;

static __device__ __forceinline__ short f2bf(float f) {
  __hip_bfloat16 h = __float2bfloat16(f);
  return *reinterpret_cast<short*>(&h);
}

// =================== K1: compress (1x1 conv) via bf16 MFMA ==============
// guide[b][y][x][c] bf16 = sum_c' feat[b][c'][y][x] * wc[c][c'] + bc[c]
// grid 1024 = 4 b x 128 y x 2 x-halves (64 px). block 256 (4 waves).
// (unchanged — HBM-bound at ~its floor, ~13 us)
__global__ __launch_bounds__(256) void k_compress(
    const float* __restrict__ feat, const float* __restrict__ wc,
    const float* __restrict__ bc, const float* __restrict__ we,
    short* __restrict__ guide, short* __restrict__ web) {
  __shared__ short Al[32 * 520];  // [(cblk*4+lh)][o(64)*8], pad 512->520
  __shared__ short Bl[64 * 72];   // [px][c 0..63], stride 72
  const int tid = threadIdx.x;
  const int bx = blockIdx.x;
  const int b = bx >> 8;
  const int y = (bx >> 1) & 127;
  const int x0 = (bx & 1) << 6;

  // distributed web prestage: web[tap][kk pad32][c], zero for kk>=25
  {
    int j = bx * 256 + tid;
    if (j < 9 * 32 * 64) {
      int tap = j >> 11, kk = (j >> 6) & 31, c = j & 63;
      float v = (kk < KK) ? we[(kk * 64 + c) * 9 + tap] : 0.f;
      web[j] = f2bf(v);
    }
  }

  // convert wc (64x256 f32) -> Al in fragment order
#pragma unroll
  for (int t = 0; t < 8; ++t) {
    int idx = tid + t * 256;  // 0..2047
    int o = idx >> 5, c8 = idx & 31;
    const f32x4* src = (const f32x4*)(wc + o * CF + c8 * 8);
    f32x4 v0 = src[0], v1 = src[1];
    short8v h;
    h[0] = f2bf(v0.x); h[1] = f2bf(v0.y); h[2] = f2bf(v0.z); h[3] = f2bf(v0.w);
    h[4] = f2bf(v1.x); h[5] = f2bf(v1.y); h[6] = f2bf(v1.z); h[7] = f2bf(v1.w);
    int cblk = c8 >> 2, lh4 = c8 & 3;
    *(short8v*)(Al + (cblk * 4 + lh4) * 520 + o * 8) = h;
  }

  const int wave = tid >> 6, l = tid & 63;
  const int l15 = l & 15, lh = l >> 4;
  const int px_s = tid & 63;          // staging pixel
  const int c_s = (tid >> 6) << 4;    // staging channel offset (16/wave)
  const float* fb = feat + (size_t)b * CF * NPIX + y * WW + x0;

  f32x4 acc[4];
#pragma unroll
  for (int m = 0; m < 4; ++m) acc[m] = (f32x4){0.f, 0.f, 0.f, 0.f};

  for (int c0 = 0; c0 < CF; c0 += 64) {
    if (c0) __syncthreads();
    float v[16];
#pragma unroll
    for (int i = 0; i < 16; ++i)
      v[i] = fb[(size_t)(c0 + c_s + i) * NPIX + px_s];
    short8v h0, h1;
#pragma unroll
    for (int e = 0; e < 8; ++e) { h0[e] = f2bf(v[e]); h1[e] = f2bf(v[8 + e]); }
    *(short8v*)(Bl + px_s * 72 + c_s) = h0;
    *(short8v*)(Bl + px_s * 72 + c_s + 8) = h1;
    __syncthreads();  // Bl (and, first pass, Al) visible
#pragma unroll
    for (int ks = 0; ks < 64; ks += 32) {
      const int cblk = (c0 + ks) >> 5;
      short8v bfr = *(const short8v*)(Bl + (wave * 16 + l15) * 72 + ks + lh * 8);
#pragma unroll
      for (int m = 0; m < 4; ++m) {
        short8v a = *(const short8v*)(Al + (cblk * 4 + lh) * 520 +
                                      (m * 16 + l15) * 8);
        acc[m] = __builtin_amdgcn_mfma_f32_16x16x32_bf16(a, bfr, acc[m], 0, 0, 0);
      }
    }
  }

  // epilogue: +bias, cvt bf16, store [b][y][x][c]
  const int px = wave * 16 + l15;
  short* gb = guide + ((size_t)((b * HH + y) * WW + x0 + px)) * CC;
#pragma unroll
  for (int m = 0; m < 4; ++m) {
    short4v o;
#pragma unroll
    for (int r = 0; r < 4; ++r) {
      int c = m * 16 + lh * 4 + r;
      o[r] = f2bf(acc[m][r] + bc[c]);
    }
    *(short4v*)(gb + m * 16 + lh * 4) = o;
  }
}

// ===== K2: conv3x3 + bias + softmax via MFMA — 4x8 tiles, 128 thr =======
// grid 2048 = 4 b x 32 y-tiles(4) x 16 x-tiles(8). block 128 (2 waves).
// 8 blocks/CU. Mask stored in coalesced chunk layout:
//   maskq[b][q(7)][Y][X][4] f32x4, chunk q holds kk 4q..4q+3 (zeros pad).
__global__ __launch_bounds__(128) void k_conv(
    const short* __restrict__ guide, const short* __restrict__ web,
    const float* __restrict__ be, float* __restrict__ maskq) {
  __shared__ short Gl[6 * 10 * 72];  // [y'(6)][x'(10)][c], stride 72
  const int tid = threadIdx.x;
  const int bx = blockIdx.x;
  const int b = bx >> 9;
  const int t = bx & 511;
  const int y0 = (t >> 4) << 2, x0 = (t & 15) << 3;
  const int wave = tid >> 6, l = tid & 63;
  const int l15 = l & 15, lh = l >> 4;

  // ---- stage guide halo tile 6x10 (zero-pad) ----
  for (int idx = tid; idx < 6 * 10 * 8; idx += 128) {
    int yp = idx / 80;
    int rem = idx - yp * 80;
    int xp = rem >> 3, cq = (rem & 7) << 3;
    int gy = y0 - 1 + yp, gx = x0 - 1 + xp;
    short8v v = {0, 0, 0, 0, 0, 0, 0, 0};
    if (gy >= 0 && gy < HH && gx >= 0 && gx < WW)
      v = *(const short8v*)(guide + ((size_t)((b * HH + gy) * WW + gx)) * CC + cq);
    *(short8v*)(Gl + (yp * 10 + xp) * 72 + cq) = v;
  }
  __syncthreads();

  // ---- conv MFMA: px = wave*16 + l15 -> (row, col) in 4x8 tile ----
  const int r_ = wave * 2 + (l15 >> 3);  // tile row 0..3
  const int cx = l15 & 7;                // tile col 0..7
  f32x4 acc0 = {0.f, 0.f, 0.f, 0.f}, acc1 = {0.f, 0.f, 0.f, 0.f};
#pragma unroll
  for (int tap = 0; tap < 9; ++tap) {
    const int dy = tap / 3, dx = tap - dy * 3;
#pragma unroll
    for (int ks = 0; ks < 64; ks += 32) {
      short8v a0 = *(const short8v*)(web + (tap * 32 + l15) * 64 + ks + lh * 8);
      short8v a1 =
          *(const short8v*)(web + (tap * 32 + 16 + l15) * 64 + ks + lh * 8);
      short8v bf = *(const short8v*)(Gl + ((r_ + dy) * 10 + cx + dx) * 72 +
                                     ks + lh * 8);
      acc0 = __builtin_amdgcn_mfma_f32_16x16x32_bf16(a0, bf, acc0, 0, 0, 0);
      acc1 = __builtin_amdgcn_mfma_f32_16x16x32_bf16(a1, bf, acc1, 0, 0, 0);
    }
  }

  // ---- bias + softmax over kk (25 vals in 4 lanes: xor 16,32) ----
  float sv[8];
#pragma unroll
  for (int r = 0; r < 4; ++r) {
    int kk0 = lh * 4 + r;            // 0..15, always < 25
    sv[r] = acc0[r] + be[kk0];
    int kk1 = 16 + lh * 4 + r;       // 16..31
    sv[4 + r] = (kk1 < KK) ? (acc1[r] + be[kk1]) : -1e30f;
  }
  float mx = sv[0];
#pragma unroll
  for (int i = 1; i < 8; ++i) mx = fmaxf(mx, sv[i]);
  mx = fmaxf(mx, __shfl_xor(mx, 16));
  mx = fmaxf(mx, __shfl_xor(mx, 32));
  float s = 0.f;
#pragma unroll
  for (int i = 0; i < 8; ++i) {
    sv[i] = __expf(sv[i] - mx);
    s += sv[i];
  }
  s += __shfl_xor(s, 16);
  s += __shfl_xor(s, 32);
  float inv = 1.f / s;

  // store: chunk q=lh (kk 4lh..) and q=4+lh (kk 16+4lh..), coalesced f32x4
  const int Y = y0 + r_, X = x0 + cx;
  const size_t pxoff = (size_t)(Y << 7) + X;
  f32x4 o0 = {sv[0] * inv, sv[1] * inv, sv[2] * inv, sv[3] * inv};
  *(f32x4*)(maskq + ((((size_t)(b * 7 + lh)) << 14) + pxoff) * 4) = o0;
  if (lh < 3) {  // chunks 4,5,6 (q=6 lanes 25..27 hold zeros)
    f32x4 o1 = {sv[4] * inv, sv[5] * inv, sv[6] * inv, sv[7] * inv};
    *(f32x4*)(maskq + ((((size_t)(b * 7 + 4 + lh)) << 14) + pxoff) * 4) = o1;
  }
}

// ================= K3: CARAFE upsample, channel-split ===================
// grid 2048 = 4 b x 256 tiles (8x8 hi-px) x 2 ch-halves (40 ch).
// block 256 = 8 groups (5 ch) x 32 px-pairs. Pl [cell 64][50] f32 (12.8 KB).
// Masks read from coalesced chunk layout maskq[b][q][Y][X][4].
__global__ __launch_bounds__(256) void k_carafe3(
    const float* __restrict__ pred, const float* __restrict__ maskq,
    float* __restrict__ out) {
  __shared__ float Pl[64 * 50];
  const int tid = threadIdx.x;
  const int bx = blockIdx.x;
  const int half = bx & 1;
  const int t = (bx >> 1) & 255;
  const int b = bx >> 9;
  const int y0 = (t >> 4) << 3, x0 = (t & 15) << 3;

  // ---- stage Pl: 40 ch x 8x8 lo cells, reflect-padded ----
  const int ylo = (y0 >> 1) - 2, xlo = (x0 >> 1) - 2;
#pragma unroll
  for (int it = 0; it < 10; ++it) {
    int idx = it * 256 + tid;          // 0..2559
    int c = idx >> 6;                  // 0..39
    int cell = idx & 63;
    int r = cell >> 3, cl = cell & 7;
    int ry = ylo + r;
    ry = ry < 0 ? -ry : (ry > 63 ? 126 - ry : ry);
    int rx = xlo + cl;
    rx = rx < 0 ? -rx : (rx > 63 ? 126 - rx : rx);
    int gg = c / 5, cc = c - gg * 5;
    Pl[cell * 50 + gg * 6 + cc] =
        pred[(((size_t)(b * CP + half * 40 + c)) << 12) + (ry << 6) + rx];
  }

  // ---- pair masks -> registers (coalesced chunk loads) ----
  const int g = tid >> 5;              // 0..7 -> 5-ch group
  const int pr = tid & 31;             // pry(0..7) x prx(0..3)
  const int pry = pr >> 2, prx = pr & 3;
  const int Y = y0 + pry, X = x0 + prx * 2;
  const size_t pxoff = (size_t)(Y << 7) + X;
  float m[2][KK];
#pragma unroll
  for (int q = 0; q < 7; ++q) {
    const float* base = maskq + ((((size_t)(b * 7 + q)) << 14) + pxoff) * 4;
    f32x4 m0 = *(const f32x4*)(base);
    f32x4 m1 = *(const f32x4*)(base + 4);
#pragma unroll
    for (int e = 0; e < 4; ++e) {
      int kk = q * 4 + e;
      if (kk < KK) { m[0][kk] = m0[e]; m[1][kk] = m1[e]; }
    }
  }
  __syncthreads();  // Pl ready

  // ---- carafe: 5 ch x 2 px per thread ----
  float acc[5][2];
#pragma unroll
  for (int cc = 0; cc < 5; ++cc) { acc[cc][0] = 0.f; acc[cc][1] = 0.f; }

  const float* Pbase = Pl + ((pry >> 1) * 8 + prx) * 50 + g * 6;
#pragma unroll
  for (int i = 0; i < 5; ++i)
#pragma unroll
    for (int j = 0; j < 5; ++j) {
      const float* P = Pbase + (i * 8 + j) * 50;
      f32x2 p01 = *(const f32x2*)(P);
      f32x2 p23 = *(const f32x2*)(P + 2);
      float p4 = P[4];
      float m0 = m[0][i * 5 + j], m1 = m[1][i * 5 + j];
      acc[0][0] += p01.x * m0; acc[0][1] += p01.x * m1;
      acc[1][0] += p01.y * m0; acc[1][1] += p01.y * m1;
      acc[2][0] += p23.x * m0; acc[2][1] += p23.x * m1;
      acc[3][0] += p23.y * m0; acc[3][1] += p23.y * m1;
      acc[4][0] += p4    * m0; acc[4][1] += p4    * m1;
    }

#pragma unroll
  for (int cc = 0; cc < 5; ++cc) {
    float* ob = out + (((size_t)(b * CP + half * 40 + g * 5 + cc)) << 14) +
                Y * WW + X;
    f32x2 v2 = {acc[cc][0], acc[cc][1]};
    *(f32x2*)ob = v2;
  }
}

extern "C" void kernel_launch(void* const* d_in, const int* in_sizes, int n_in,
                              void* d_out, int out_size, void* d_ws,
                              size_t ws_size, hipStream_t stream) {
  (void)in_sizes; (void)n_in; (void)out_size; (void)ws_size;
  const float* pred = (const float*)d_in[0];  // (4,80,64,64)
  const float* feat = (const float*)d_in[1];  // (4,256,128,128)
  const float* wc   = (const float*)d_in[2];  // (64,256)
  const float* bc   = (const float*)d_in[3];  // (64)
  const float* we   = (const float*)d_in[4];  // (25,64,3,3)
  const float* be   = (const float*)d_in[5];  // (25)
  float* out = (float*)d_out;                 // (4,80,128,128)

  char* ws = (char*)d_ws;
  short* guide = (short*)ws;                    // 8,388,608 B bf16 [b][y][x][c]
  short* web   = (short*)(ws + 8388608);        // 36,864 B bf16 [tap][kk32][c]
  float* maskq = (float*)(ws + 8388608 + 36864);// 7,340,032 B f32 [b][7][Y][X][4]

  hipLaunchKernelGGL(k_compress, dim3(1024), dim3(256), 0, stream,
                     feat, wc, bc, we, guide, web);
  hipLaunchKernelGGL(k_conv, dim3(2048), dim3(128), 0, stream,
                     guide, web, be, maskq);
  hipLaunchKernelGGL(k_carafe3, dim3(2048), dim3(256), 0, stream,
                     pred, maskq, out);
}